// Round 10
// baseline (738.110 us; speedup 1.0000x reference)
//
#include <hip/hip_runtime.h>
#include <stdint.h>

typedef unsigned short u16;
typedef __bf16 bf16x8 __attribute__((ext_vector_type(8)));
typedef float f32x4 __attribute__((ext_vector_type(4)));

#define MFMA16(a, b, c) __builtin_amdgcn_mfma_f32_16x16x32_bf16((a), (b), (c), 0, 0, 0)

// Native HW conversion (v_cvt_pk_bf16_f32, RNE).
__device__ __forceinline__ u16 f2bf(float f) {
  union { __bf16 h; u16 u; } v;
  v.h = (__bf16)f;
  return v.u;
}

// NaN-squashing exp: fmaxf(NaN, -80) == -80, so bad inputs give ~0, not NaN.
__device__ __forceinline__ float expf_c(float x) {
  return __expf(fmaxf(x, -80.0f));
}

// Async global->LDS, 16 B per lane. LDS dest must be WAVE-UNIFORM (HW applies
// +lane*16); global src is per-lane (pre-swizzle the SOURCE, keep LDS linear).
__device__ __forceinline__ void gl_lds16(const u16* g, u16* l) {
  __builtin_amdgcn_global_load_lds(
      (const __attribute__((address_space(1))) unsigned int*)g,
      (__attribute__((address_space(3))) unsigned int*)l, 16, 0, 0);
}

// ---------------------------------------------------------------------------
// f32 -> bf16 bulk converts. z selects tensor; 8 elems/thread.
// ---------------------------------------------------------------------------
struct Cvt6Args {
  const float* s0; const float* s1; const float* s2;
  const float* s3; const float* s4; const float* s5;
  u16* d0; u16* d1; u16* d2; u16* d3; u16* d4; u16* d5;
};

__global__ __launch_bounds__(256) void cvt6(Cvt6Args a) {
  const int z = blockIdx.y;
  const float* s; u16* d; int n8;
  if (z == 0)      { s = a.s0; d = a.d0; n8 = (4 * 1024 * 1024) / 8; }
  else if (z == 1) { s = a.s1; d = a.d1; n8 = (4 * 1024 * 1024) / 8; }
  else if (z == 2) { s = a.s2; d = a.d2; n8 = (4 * 1024 * 1024) / 8; }
  else if (z == 3) { s = a.s3; d = a.d3; n8 = (1024 * 1024) / 8; }
  else if (z == 4) { s = a.s4; d = a.d4; n8 = (1024 * 1024) / 8; }
  else             { s = a.s5; d = a.d5; n8 = (1024 * 1024) / 8; }
  const int i = blockIdx.x * 256 + threadIdx.x;
  if (i >= n8) return;
  float4 f0 = ((const float4*)s)[2 * i];
  float4 f1 = ((const float4*)s)[2 * i + 1];
  ushort4 h0, h1;
  h0.x = f2bf(f0.x); h0.y = f2bf(f0.y); h0.z = f2bf(f0.z); h0.w = f2bf(f0.w);
  h1.x = f2bf(f1.x); h1.y = f2bf(f1.y); h1.z = f2bf(f1.z); h1.w = f2bf(f1.w);
  ((ushort4*)d)[2 * i] = h0;
  ((ushort4*)d)[2 * i + 1] = h1;
}

__global__ __launch_bounds__(256) void cvt_one(const float* __restrict__ s,
                                               u16* __restrict__ d) {
  const int i = blockIdx.x * 256 + threadIdx.x;  // n8 = 1M/8 = 131072
  if (i >= (1024 * 1024) / 8) return;
  float4 f0 = ((const float4*)s)[2 * i];
  float4 f1 = ((const float4*)s)[2 * i + 1];
  ushort4 h0, h1;
  h0.x = f2bf(f0.x); h0.y = f2bf(f0.y); h0.z = f2bf(f0.z); h0.w = f2bf(f0.w);
  h1.x = f2bf(f1.x); h1.y = f2bf(f1.y); h1.z = f2bf(f1.z); h1.w = f2bf(f1.w);
  ((ushort4*)d)[2 * i] = h0;
  ((ushort4*)d)[2 * i + 1] = h1;
}

// ---------------------------------------------------------------------------
// y = x @ W^T GEMM core, templated on BM (M-tile). BN=128, BK=64. X, W are
// PRE-CONVERTED bf16. LINEAR LDS filled by global_load_lds (16B/lane),
// XOR-swizzle slot^=(row&7) on the GLOBAL source and the fragment read.
// BM=128: 4 waves 2x2, each 64x64 (acc 4x4).  [qkv projections]
// BM=64 : 4 waves 1x4, each 64x32 (acc 4x2) — doubles grid for co-residency.
// Grid: blockIdx.x = N-tile (XCD-pins each W panel), blockIdx.y = M-tile.
// omode 0: bf16 row-major [m][n], scaled; 1: bf16 Vt[b][h][e][t]; 2: f32.
// ---------------------------------------------------------------------------
template <int BM>
__device__ __forceinline__ void gemm_core(const u16* __restrict__ X,
                                          const u16* __restrict__ W,
                                          void* __restrict__ Yv, float scale,
                                          int omode) {
  constexpr int NF = (BM == 128) ? 4 : 2;     // N fragments per wave
  constexpr int ASEG = BM / 8;                // 1KB segments in A tile
  constexpr int CNT = (ASEG + 16) / 4;        // gl_lds issues per wave
  __shared__ __align__(16) u16 lA[BM * 64];
  __shared__ __align__(16) u16 lB[128 * 64];
  const int tid = threadIdx.x;
  const int lane = tid & 63, w = tid >> 6;
  const int l15 = lane & 15, quad = lane >> 4;
  const int wm = (BM == 128) ? (w >> 1) * 64 : 0;
  const int wn = (BM == 128) ? (w & 1) * 64 : w * 32;
  const int n0 = blockIdx.x * 128, m0 = blockIdx.y * BM;

  f32x4 acc[4][NF];
#pragma unroll
  for (int m = 0; m < 4; ++m)
#pragma unroll
    for (int n = 0; n < NF; ++n) acc[m][n] = (f32x4){0.f, 0.f, 0.f, 0.f};

  const int row8 = lane >> 3;   // row within 8-row segment
  const int slot = lane & 7;    // 16B slot within 128B row
  const int scol = ((slot ^ row8) << 3);  // pre-swizzled source column (u16)

  for (int kk = 0; kk < 1024; kk += 64) {
    __syncthreads();
#pragma unroll
    for (int ps = 0; ps < CNT; ++ps) {
      const int s = w * CNT + ps;
      if (s < ASEG) {
        const int row = s * 8 + row8;
        gl_lds16(&X[(size_t)(m0 + row) * 1024 + kk + scol], &lA[s * 512]);
      } else {
        const int s2 = s - ASEG;
        const int row = s2 * 8 + row8;
        gl_lds16(&W[(size_t)(n0 + row) * 1024 + kk + scol], &lB[s2 * 512]);
      }
    }
    __syncthreads();  // compiler drains vmcnt(0) before s_barrier
    bf16x8 af[2][4], bfr[2][NF];
#pragma unroll
    for (int h = 0; h < 2; ++h) {
#pragma unroll
      for (int m = 0; m < 4; ++m) {
        const int rA = wm + m * 16 + l15;
        af[h][m] = *(const bf16x8*)&lA[rA * 64 + (((quad + 4 * h) ^ (rA & 7)) << 3)];
      }
#pragma unroll
      for (int n = 0; n < NF; ++n) {
        const int rB = wn + n * 16 + l15;
        bfr[h][n] = *(const bf16x8*)&lB[rB * 64 + (((quad + 4 * h) ^ (rB & 7)) << 3)];
      }
    }
#pragma unroll
    for (int h = 0; h < 2; ++h)
#pragma unroll
      for (int m = 0; m < 4; ++m)
#pragma unroll
        for (int n = 0; n < NF; ++n)
          acc[m][n] = MFMA16(af[h][m], bfr[h][n], acc[m][n]);
  }

  if (omode == 0) {
    u16* Y = (u16*)Yv;
#pragma unroll
    for (int m = 0; m < 4; ++m) {
      int grow0 = m0 + wm + m * 16 + quad * 4;
#pragma unroll
      for (int n = 0; n < NF; ++n) {
        int gcol = n0 + wn + n * 16 + l15;
#pragma unroll
        for (int r = 0; r < 4; ++r)
          Y[(size_t)(grow0 + r) * 1024 + gcol] = f2bf(acc[m][n][r] * scale);
      }
    }
  } else if (omode == 1) {
    // Vt[((b*16+h)*64+e)*2048 + t]; 4 consecutive t per acc -> 8B packed stores
    u16* Y = (u16*)Yv;
#pragma unroll
    for (int m = 0; m < 4; ++m) {
      int grow0 = m0 + wm + m * 16 + quad * 4;
      int bb = grow0 >> 11, t = grow0 & 2047;
#pragma unroll
      for (int n = 0; n < NF; ++n) {
        int gcol = n0 + wn + n * 16 + l15;
        int hh = gcol >> 6, e = gcol & 63;
        ushort4 pk;
        pk.x = f2bf(acc[m][n][0]);
        pk.y = f2bf(acc[m][n][1]);
        pk.z = f2bf(acc[m][n][2]);
        pk.w = f2bf(acc[m][n][3]);
        *(ushort4*)&Y[((size_t)((bb * 16 + hh) * 64 + e)) * 2048 + t] = pk;
      }
    }
  } else {
    float* Y = (float*)Yv;
#pragma unroll
    for (int m = 0; m < 4; ++m) {
      int grow0 = m0 + wm + m * 16 + quad * 4;
#pragma unroll
      for (int n = 0; n < NF; ++n) {
        int gcol = n0 + wn + n * 16 + l15;
#pragma unroll
        for (int r = 0; r < 4; ++r)
          Y[(size_t)(grow0 + r) * 1024 + gcol] = acc[m][n][r] * scale;
      }
    }
  }
}

// Fused Q/K/V projection: grid.z selects which projection a block computes.
struct QKVArgs {
  const u16* X0; const u16* X1; const u16* X2;
  const u16* W0; const u16* W1; const u16* W2;
  void* Y0; void* Y1; void* Y2;
  float s0, s1, s2;
};

__global__ __launch_bounds__(256, 2) void proj_qkv(QKVArgs a) {
  const u16* X; const u16* W; void* Y; float sc; int om;
  if (blockIdx.z == 0)      { X = a.X0; W = a.W0; Y = a.Y0; sc = a.s0; om = 0; }
  else if (blockIdx.z == 1) { X = a.X1; W = a.W1; Y = a.Y1; sc = a.s1; om = 0; }
  else                      { X = a.X2; W = a.W2; Y = a.Y2; sc = a.s2; om = 1; }
  gemm_core<64>(X, W, Y, sc, om);
}

__global__ __launch_bounds__(256, 2) void proj_out(const u16* __restrict__ Xv,
                                                   const u16* __restrict__ W,
                                                   void* __restrict__ Yv) {
  gemm_core<64>(Xv, W, Yv, 1.0f, 2);
}

// ---------------------------------------------------------------------------
// Fused causal attention, two-pass, swapped QK^T, occupancy-tuned.
// (unchanged from round 8/9 — attn is within ~1.5x of its traffic floor)
// ---------------------------------------------------------------------------
__global__ __launch_bounds__(256, 4) void attn_kernel(const u16* __restrict__ Qb,
                                                      const u16* __restrict__ Kb,
                                                      const u16* __restrict__ Vt,
                                                      float* __restrict__ attnF,
                                                      u16* __restrict__ Ob) {
  __shared__ __align__(16) u16 lK[64 * 72];
  __shared__ __align__(16) u16 lV[64 * 72];
  __shared__ __align__(16) u16 lP[4][16 * 72];

  const int bid = blockIdx.x;
  const int qt = bid >> 5;      // consecutive bids differ in bh, not qt
  const int bh = bid & 31;
  const int b = bh >> 4, h = bh & 15;
  const int q0 = qt * 64;
  const int tid = threadIdx.x;
  const int w = tid >> 6, lane = tid & 63;
  const int l15 = lane & 15, quad = lane >> 4;
  const f32x4 ZERO4 = {0.f, 0.f, 0.f, 0.f};

  // zero-fill strictly-upper (masked) columns: each wave-instruction writes
  // 64 lanes x 16B = 1KB CONTIGUOUS within one row.
  {
    const int kz0 = q0 + 64;
    if (kz0 < 2048) {
      for (int r = w; r < 64; r += 4) {
        size_t base = ((size_t)bh * 2048 + q0 + r) * 2048;
        uint4 z = {0, 0, 0, 0};
        for (int c = kz0 + lane * 4; c < 2048; c += 256)
          *(uint4*)&attnF[base + c] = z;
      }
    }
  }

  // Q fragment (B-operand: lane = q-col l15, k-dim quad*8), loaded once.
  const int qrow = q0 + w * 16 + l15;  // this thread's q row (global t)
  const size_t qrowbase = (size_t)(b * 2048 + qrow) * 1024 + h * 64;
  const bf16x8 aq0 = *(const bf16x8*)&Qb[qrowbase + quad * 8];
  const bf16x8 aq1 = *(const bf16x8*)&Qb[qrowbase + 32 + quad * 8];

  const int kq = quad * 4;                           // key sub-offset (C rows)
  const int srow = tid >> 3, sseg = (tid & 7) * 8;   // staging mapping

  // ---- pass 1: lacc = per-row sum of exp(s) ----
  float lacc = 0.f;
  for (int c = 0; c <= qt; ++c) {
    const int k0 = c * 64;
    __syncthreads();
#pragma unroll
    for (int p = 0; p < 2; ++p) {
      int rr = p * 32 + srow;
      *(uint4*)&lK[rr * 72 + sseg] =
          *(const uint4*)&Kb[(size_t)(b * 2048 + k0 + rr) * 1024 + h * 64 + sseg];
    }
    __syncthreads();
#pragma unroll
    for (int n = 0; n < 4; ++n) {
      bf16x8 bk0 = *(const bf16x8*)&lK[(n * 16 + l15) * 72 + quad * 8];
      bf16x8 bk1 = *(const bf16x8*)&lK[(n * 16 + l15) * 72 + 32 + quad * 8];
      f32x4 s = MFMA16(bk0, aq0, ZERO4);
      s = MFMA16(bk1, aq1, s);
      const int keyb = k0 + n * 16 + kq;
      if (c == qt) {
#pragma unroll
        for (int i = 0; i < 4; ++i)
          lacc += (keyb + i > qrow) ? 0.f : expf_c(s[i]);
      } else {
#pragma unroll
        for (int i = 0; i < 4; ++i) lacc += expf_c(s[i]);
      }
    }
  }
  // lanes sharing l15 (same q-row) differ in bits 4,5 -> 2-step reduce
  lacc += __shfl_xor(lacc, 16);
  lacc += __shfl_xor(lacc, 32);
  const float invl = 1.0f / fmaxf(lacc, 1e-30f);

  // ---- pass 2: normalized P -> attnF ; O += P·V ----
  f32x4 o[4];
#pragma unroll
  for (int n = 0; n < 4; ++n) o[n] = ZERO4;
  const size_t arow = ((size_t)bh * 2048 + qrow) * 2048;
  u16* lPw = lP[w];

  for (int c = 0; c <= qt; ++c) {
    const int k0 = c * 64;
    __syncthreads();
#pragma unroll
    for (int p = 0; p < 2; ++p) {
      int rr = p * 32 + srow;
      *(uint4*)&lK[rr * 72 + sseg] =
          *(const uint4*)&Kb[(size_t)(b * 2048 + k0 + rr) * 1024 + h * 64 + sseg];
      *(uint4*)&lV[rr * 72 + sseg] =
          *(const uint4*)&Vt[((size_t)bh * 64 + rr) * 2048 + k0 + sseg];
    }
    __syncthreads();
    const bool diag = (c == qt);
#pragma unroll
    for (int n = 0; n < 4; ++n) {
      bf16x8 bk0 = *(const bf16x8*)&lK[(n * 16 + l15) * 72 + quad * 8];
      bf16x8 bk1 = *(const bf16x8*)&lK[(n * 16 + l15) * 72 + 32 + quad * 8];
      f32x4 s = MFMA16(bk0, aq0, ZERO4);
      s = MFMA16(bk1, aq1, s);
      const int keyb = k0 + n * 16 + kq;
#pragma unroll
      for (int i = 0; i < 4; ++i) {
        float pv = expf_c(s[i]) * invl;
        if (diag && keyb + i > qrow) pv = 0.f;  // causal mask (exact zero)
        s[i] = pv;
      }
      *(f32x4*)&attnF[arow + keyb] = s;        // 16B coalesced, final value
      ushort4 pk;
      pk.x = f2bf(s[0]); pk.y = f2bf(s[1]); pk.z = f2bf(s[2]); pk.w = f2bf(s[3]);
      *(ushort4*)&lPw[l15 * 72 + n * 16 + kq] = pk;  // P[q_local][key_local]
    }
    // lP is wave-private: RAW through LDS within a wave needs no barrier.
#pragma unroll
    for (int kkk = 0; kkk < 2; ++kkk) {
      bf16x8 ap = *(const bf16x8*)&lPw[l15 * 72 + kkk * 32 + quad * 8];
#pragma unroll
      for (int n = 0; n < 4; ++n) {
        bf16x8 bv = *(const bf16x8*)&lV[(n * 16 + l15) * 72 + kkk * 32 + quad * 8];
        o[n] = MFMA16(ap, bv, o[n]);
      }
    }
  }

  // ---- write O tile (bf16, row-major [b*T+t][D]) via LDS for coalescing ----
  // o[n][i]: q_local = quad*4+i, e_local = n*16+l15 (already normalized)
#pragma unroll
  for (int n = 0; n < 4; ++n)
#pragma unroll
    for (int i = 0; i < 4; ++i) {
      float ov = o[n][i];
      if (!(ov == ov)) ov = 0.f;  // sanitize: guarantee finite output
      lPw[(quad * 4 + i) * 72 + n * 16 + l15] = f2bf(ov);
    }
  {
    int prow = lane >> 3, pseg = (lane & 7) * 8;
#pragma unroll
    for (int p2 = 0; p2 < 2; ++p2) {
      int rr = p2 * 8 + prow;
      *(uint4*)&Ob[(size_t)(b * 2048 + q0 + w * 16 + rr) * 1024 + h * 64 + pseg] =
          *(const uint4*)&lPw[rr * 72 + pseg];
    }
  }
}

extern "C" void kernel_launch(void* const* d_in, const int* in_sizes, int n_in,
                              void* d_out, int out_size, void* d_ws, size_t ws_size,
                              hipStream_t stream) {
  const float* q  = (const float*)d_in[0];
  const float* k  = (const float*)d_in[1];
  const float* v  = (const float*)d_in[2];
  const float* Wq = (const float*)d_in[3];
  const float* Wk = (const float*)d_in[4];
  const float* Wv = (const float*)d_in[5];
  const float* Wc = (const float*)d_in[6];
  // d_in[7] = causal mask: computed analytically, unused.

  float* outF  = (float*)d_out;                   // [B*T, D] = 4096x1024 f32
  float* attnF = outF + (size_t)4096 * 1024;      // [B, H, T, T] f32

  const size_t BUF  = (size_t)4096 * 1024;        // u16 elems per staging buffer
  const size_t WBUF = (size_t)1024 * 1024;        // u16 elems per weight buffer
  u16* ws = (u16*)d_ws;
  const bool big_ws = ws_size >= 4 * BUF * sizeof(u16);

  u16 *Qb, *Kb, *Vt, *Ob;
  if (big_ws) {
    Qb = ws; Kb = ws + BUF; Vt = ws + 2 * BUF; Ob = ws + 3 * BUF;
  } else {
    // out region is 16.8 MB f32 = room for two bf16 staging buffers.
    Qb = (u16*)outF; Ob = (u16*)outF + BUF; Kb = ws; Vt = ws + BUF;
  }

  // bf16 copies of inputs live in the attnF region, which is pure scratch
  // until attn_kernel (stream-ordered after proj_qkv) overwrites all of it.
  u16* qbf  = (u16*)attnF;
  u16* kbf  = qbf  + BUF;
  u16* vbf  = kbf  + BUF;
  u16* wqbf = vbf  + BUF;
  u16* wkbf = wqbf + WBUF;
  u16* wvbf = wkbf + WBUF;
  // Wc is converted AFTER attn into the then-dead Vt region (both ws layouts).
  u16* wcbf = Vt;

  dim3 blk(256, 1, 1);

  Cvt6Args ca;
  ca.s0 = q;    ca.s1 = k;    ca.s2 = v;
  ca.s3 = Wq;   ca.s4 = Wk;   ca.s5 = Wv;
  ca.d0 = qbf;  ca.d1 = kbf;  ca.d2 = vbf;
  ca.d3 = wqbf; ca.d4 = wkbf; ca.d5 = wvbf;
  cvt6<<<dim3(2048, 6), blk, 0, stream>>>(ca);

  QKVArgs a;
  a.X0 = qbf;  a.X1 = kbf;  a.X2 = vbf;
  a.W0 = wqbf; a.W1 = wkbf; a.W2 = wvbf;
  a.Y0 = Qb; a.Y1 = Kb; a.Y2 = Vt;
  a.s0 = 0.03125f;  // fold 1/TEMPERATURE = 1/32 into Q projection
  a.s1 = 1.0f; a.s2 = 1.0f;
  proj_qkv<<<dim3(8, 64, 3), blk, 0, stream>>>(a);
  attn_kernel<<<dim3(1024), blk, 0, stream>>>(Qb, Kb, Vt, attnF, Ob);

  // Vt is dead after attn: reuse it for the bf16 copy of Wc.
  cvt_one<<<dim3(512), blk, 0, stream>>>(Wc, wcbf);

  const u16* gemm_src = Ob;
  if (!big_ws) {
    // Kb is dead now; move Ob out of the out region so the final f32 GEMM
    // never reads and writes overlapping memory.
    (void)hipMemcpyAsync(ws, Ob, BUF * sizeof(u16), hipMemcpyDeviceToDevice, stream);
    gemm_src = ws;
  }
  proj_out<<<dim3(8, 64), blk, 0, stream>>>(gemm_src, wcbf, outF);
}

// Round 11
// 727.817 us; speedup vs baseline: 1.0141x; 1.0141x over previous
//
#include <hip/hip_runtime.h>
#include <stdint.h>

typedef unsigned short u16;
typedef __bf16 bf16x8 __attribute__((ext_vector_type(8)));
typedef float f32x4 __attribute__((ext_vector_type(4)));

#define MFMA16(a, b, c) __builtin_amdgcn_mfma_f32_16x16x32_bf16((a), (b), (c), 0, 0, 0)

// Native HW conversion (v_cvt_pk_bf16_f32, RNE).
__device__ __forceinline__ u16 f2bf(float f) {
  union { __bf16 h; u16 u; } v;
  v.h = (__bf16)f;
  return v.u;
}

// NaN-squashing exp: fmaxf(NaN, -80) == -80, so bad inputs give ~0, not NaN.
__device__ __forceinline__ float expf_c(float x) {
  return __expf(fmaxf(x, -80.0f));
}

// Async global->LDS, 16 B per lane. LDS dest must be WAVE-UNIFORM (HW applies
// +lane*16); global src is per-lane (pre-swizzle the SOURCE, keep LDS linear).
__device__ __forceinline__ void gl_lds16(const u16* g, u16* l) {
  __builtin_amdgcn_global_load_lds(
      (const __attribute__((address_space(1))) unsigned int*)g,
      (__attribute__((address_space(3))) unsigned int*)l, 16, 0, 0);
}

// ---------------------------------------------------------------------------
// f32 -> bf16 bulk converts. z selects tensor; 8 elems/thread.
// ---------------------------------------------------------------------------
struct Cvt6Args {
  const float* s0; const float* s1; const float* s2;
  const float* s3; const float* s4; const float* s5;
  u16* d0; u16* d1; u16* d2; u16* d3; u16* d4; u16* d5;
};

__global__ __launch_bounds__(256) void cvt6(Cvt6Args a) {
  const int z = blockIdx.y;
  const float* s; u16* d; int n8;
  if (z == 0)      { s = a.s0; d = a.d0; n8 = (4 * 1024 * 1024) / 8; }
  else if (z == 1) { s = a.s1; d = a.d1; n8 = (4 * 1024 * 1024) / 8; }
  else if (z == 2) { s = a.s2; d = a.d2; n8 = (4 * 1024 * 1024) / 8; }
  else if (z == 3) { s = a.s3; d = a.d3; n8 = (1024 * 1024) / 8; }
  else if (z == 4) { s = a.s4; d = a.d4; n8 = (1024 * 1024) / 8; }
  else             { s = a.s5; d = a.d5; n8 = (1024 * 1024) / 8; }
  const int i = blockIdx.x * 256 + threadIdx.x;
  if (i >= n8) return;
  float4 f0 = ((const float4*)s)[2 * i];
  float4 f1 = ((const float4*)s)[2 * i + 1];
  ushort4 h0, h1;
  h0.x = f2bf(f0.x); h0.y = f2bf(f0.y); h0.z = f2bf(f0.z); h0.w = f2bf(f0.w);
  h1.x = f2bf(f1.x); h1.y = f2bf(f1.y); h1.z = f2bf(f1.z); h1.w = f2bf(f1.w);
  ((ushort4*)d)[2 * i] = h0;
  ((ushort4*)d)[2 * i + 1] = h1;
}

__global__ __launch_bounds__(256) void cvt_one(const float* __restrict__ s,
                                               u16* __restrict__ d) {
  const int i = blockIdx.x * 256 + threadIdx.x;  // n8 = 1M/8 = 131072
  if (i >= (1024 * 1024) / 8) return;
  float4 f0 = ((const float4*)s)[2 * i];
  float4 f1 = ((const float4*)s)[2 * i + 1];
  ushort4 h0, h1;
  h0.x = f2bf(f0.x); h0.y = f2bf(f0.y); h0.z = f2bf(f0.z); h0.w = f2bf(f0.w);
  h1.x = f2bf(f1.x); h1.y = f2bf(f1.y); h1.z = f2bf(f1.z); h1.w = f2bf(f1.w);
  ((ushort4*)d)[2 * i] = h0;
  ((ushort4*)d)[2 * i + 1] = h1;
}

// ---------------------------------------------------------------------------
// y = x @ W^T GEMM core, templated on BM (M-tile). BN=128, BK=64. X, W are
// PRE-CONVERTED bf16. LINEAR LDS filled by global_load_lds (16B/lane),
// XOR-swizzle slot^=(row&7) on the GLOBAL source and the fragment read.
// (unchanged from round 10 — GEMMs are near their small-K structural cost)
// ---------------------------------------------------------------------------
template <int BM>
__device__ __forceinline__ void gemm_core(const u16* __restrict__ X,
                                          const u16* __restrict__ W,
                                          void* __restrict__ Yv, float scale,
                                          int omode) {
  constexpr int NF = (BM == 128) ? 4 : 2;     // N fragments per wave
  constexpr int ASEG = BM / 8;                // 1KB segments in A tile
  constexpr int CNT = (ASEG + 16) / 4;        // gl_lds issues per wave
  __shared__ __align__(16) u16 lA[BM * 64];
  __shared__ __align__(16) u16 lB[128 * 64];
  const int tid = threadIdx.x;
  const int lane = tid & 63, w = tid >> 6;
  const int l15 = lane & 15, quad = lane >> 4;
  const int wm = (BM == 128) ? (w >> 1) * 64 : 0;
  const int wn = (BM == 128) ? (w & 1) * 64 : w * 32;
  const int n0 = blockIdx.x * 128, m0 = blockIdx.y * BM;

  f32x4 acc[4][NF];
#pragma unroll
  for (int m = 0; m < 4; ++m)
#pragma unroll
    for (int n = 0; n < NF; ++n) acc[m][n] = (f32x4){0.f, 0.f, 0.f, 0.f};

  const int row8 = lane >> 3;   // row within 8-row segment
  const int slot = lane & 7;    // 16B slot within 128B row
  const int scol = ((slot ^ row8) << 3);  // pre-swizzled source column (u16)

  for (int kk = 0; kk < 1024; kk += 64) {
    __syncthreads();
#pragma unroll
    for (int ps = 0; ps < CNT; ++ps) {
      const int s = w * CNT + ps;
      if (s < ASEG) {
        const int row = s * 8 + row8;
        gl_lds16(&X[(size_t)(m0 + row) * 1024 + kk + scol], &lA[s * 512]);
      } else {
        const int s2 = s - ASEG;
        const int row = s2 * 8 + row8;
        gl_lds16(&W[(size_t)(n0 + row) * 1024 + kk + scol], &lB[s2 * 512]);
      }
    }
    __syncthreads();  // compiler drains vmcnt(0) before s_barrier
    bf16x8 af[2][4], bfr[2][NF];
#pragma unroll
    for (int h = 0; h < 2; ++h) {
#pragma unroll
      for (int m = 0; m < 4; ++m) {
        const int rA = wm + m * 16 + l15;
        af[h][m] = *(const bf16x8*)&lA[rA * 64 + (((quad + 4 * h) ^ (rA & 7)) << 3)];
      }
#pragma unroll
      for (int n = 0; n < NF; ++n) {
        const int rB = wn + n * 16 + l15;
        bfr[h][n] = *(const bf16x8*)&lB[rB * 64 + (((quad + 4 * h) ^ (rB & 7)) << 3)];
      }
    }
#pragma unroll
    for (int h = 0; h < 2; ++h)
#pragma unroll
      for (int m = 0; m < 4; ++m)
#pragma unroll
        for (int n = 0; n < NF; ++n)
          acc[m][n] = MFMA16(af[h][m], bfr[h][n], acc[m][n]);
  }

  if (omode == 0) {
    u16* Y = (u16*)Yv;
#pragma unroll
    for (int m = 0; m < 4; ++m) {
      int grow0 = m0 + wm + m * 16 + quad * 4;
#pragma unroll
      for (int n = 0; n < NF; ++n) {
        int gcol = n0 + wn + n * 16 + l15;
#pragma unroll
        for (int r = 0; r < 4; ++r)
          Y[(size_t)(grow0 + r) * 1024 + gcol] = f2bf(acc[m][n][r] * scale);
      }
    }
  } else if (omode == 1) {
    // Vt[((b*16+h)*64+e)*2048 + t]; 4 consecutive t per acc -> 8B packed stores
    u16* Y = (u16*)Yv;
#pragma unroll
    for (int m = 0; m < 4; ++m) {
      int grow0 = m0 + wm + m * 16 + quad * 4;
      int bb = grow0 >> 11, t = grow0 & 2047;
#pragma unroll
      for (int n = 0; n < NF; ++n) {
        int gcol = n0 + wn + n * 16 + l15;
        int hh = gcol >> 6, e = gcol & 63;
        ushort4 pk;
        pk.x = f2bf(acc[m][n][0]);
        pk.y = f2bf(acc[m][n][1]);
        pk.z = f2bf(acc[m][n][2]);
        pk.w = f2bf(acc[m][n][3]);
        *(ushort4*)&Y[((size_t)((bb * 16 + hh) * 64 + e)) * 2048 + t] = pk;
      }
    }
  } else {
    float* Y = (float*)Yv;
#pragma unroll
    for (int m = 0; m < 4; ++m) {
      int grow0 = m0 + wm + m * 16 + quad * 4;
#pragma unroll
      for (int n = 0; n < NF; ++n) {
        int gcol = n0 + wn + n * 16 + l15;
#pragma unroll
        for (int r = 0; r < 4; ++r)
          Y[(size_t)(grow0 + r) * 1024 + gcol] = acc[m][n][r] * scale;
      }
    }
  }
}

// Fused Q/K/V projection: grid.z selects which projection a block computes.
struct QKVArgs {
  const u16* X0; const u16* X1; const u16* X2;
  const u16* W0; const u16* W1; const u16* W2;
  void* Y0; void* Y1; void* Y2;
  float s0, s1, s2;
};

__global__ __launch_bounds__(256, 2) void proj_qkv(QKVArgs a) {
  const u16* X; const u16* W; void* Y; float sc; int om;
  if (blockIdx.z == 0)      { X = a.X0; W = a.W0; Y = a.Y0; sc = a.s0; om = 0; }
  else if (blockIdx.z == 1) { X = a.X1; W = a.W1; Y = a.Y1; sc = a.s1; om = 0; }
  else                      { X = a.X2; W = a.W2; Y = a.Y2; sc = a.s2; om = 1; }
  gemm_core<64>(X, W, Y, sc, om);
}

__global__ __launch_bounds__(256, 2) void proj_out(const u16* __restrict__ Xv,
                                                   const u16* __restrict__ W,
                                                   void* __restrict__ Yv) {
  gemm_core<64>(Xv, W, Yv, 1.0f, 2);
}

// ---------------------------------------------------------------------------
// Fused causal attention, two-pass, swapped QK^T, PIPELINED STAGING.
// Round-11 change: both passes use 2-deep LDS double-buffering with ONE
// barrier per chunk (was 2): per iteration, issue next-chunk global loads
// into registers BEFORE the compute (latency hides under QK^T/exp/PV),
// write them to buf[cur^1] AFTER the compute, then barrier. The trailing
// barrier keeps all waves in the same iteration, so reads (buf[cur]) and
// writes (buf[cur^1]) never touch the same buffer. LDS 46 KB -> 3 blocks/CU
// (down from 4), but barrier count halves and staging leaves the critical
// path. Work mapping (qt=bid>>5) and all arithmetic unchanged from round 8.
// ---------------------------------------------------------------------------
__global__ __launch_bounds__(256, 3) void attn_kernel(const u16* __restrict__ Qb,
                                                      const u16* __restrict__ Kb,
                                                      const u16* __restrict__ Vt,
                                                      float* __restrict__ attnF,
                                                      u16* __restrict__ Ob) {
  __shared__ __align__(16) u16 lK[2][64 * 72];
  __shared__ __align__(16) u16 lV[2][64 * 72];
  __shared__ __align__(16) u16 lP[4][16 * 72];

  const int bid = blockIdx.x;
  const int qt = bid >> 5;      // consecutive bids differ in bh, not qt
  const int bh = bid & 31;
  const int b = bh >> 4, h = bh & 15;
  const int q0 = qt * 64;
  const int tid = threadIdx.x;
  const int w = tid >> 6, lane = tid & 63;
  const int l15 = lane & 15, quad = lane >> 4;
  const f32x4 ZERO4 = {0.f, 0.f, 0.f, 0.f};

  // zero-fill strictly-upper (masked) columns: each wave-instruction writes
  // 64 lanes x 16B = 1KB CONTIGUOUS within one row.
  {
    const int kz0 = q0 + 64;
    if (kz0 < 2048) {
      for (int r = w; r < 64; r += 4) {
        size_t base = ((size_t)bh * 2048 + q0 + r) * 2048;
        uint4 z = {0, 0, 0, 0};
        for (int c = kz0 + lane * 4; c < 2048; c += 256)
          *(uint4*)&attnF[base + c] = z;
      }
    }
  }

  // Q fragment (B-operand: lane = q-col l15, k-dim quad*8), loaded once.
  const int qrow = q0 + w * 16 + l15;  // this thread's q row (global t)
  const size_t qrowbase = (size_t)(b * 2048 + qrow) * 1024 + h * 64;
  const bf16x8 aq0 = *(const bf16x8*)&Qb[qrowbase + quad * 8];
  const bf16x8 aq1 = *(const bf16x8*)&Qb[qrowbase + 32 + quad * 8];

  const int kq = quad * 4;                           // key sub-offset (C rows)
  const int srow = tid >> 3, sseg = (tid & 7) * 8;   // staging mapping
  const size_t kbase = (size_t)b * 2048 * 1024 + h * 64 + sseg;
  const size_t vbase = (size_t)bh * 64 * 2048 + sseg;

  // ---- pass 1: lacc = per-row sum of exp(s); K double-buffered ----
  float lacc = 0.f;
  {
    uint4 a0 = *(const uint4*)&Kb[kbase + (size_t)srow * 1024];
    uint4 a1 = *(const uint4*)&Kb[kbase + (size_t)(32 + srow) * 1024];
    *(uint4*)&lK[0][srow * 72 + sseg] = a0;
    *(uint4*)&lK[0][(32 + srow) * 72 + sseg] = a1;
  }
  __syncthreads();
  for (int c = 0; c <= qt; ++c) {
    const int k0 = c * 64, cur = c & 1;
    const bool pf = (c < qt);
    uint4 p0, p1;
    if (pf) {  // issue next-chunk loads; latency hides under compute below
      p0 = *(const uint4*)&Kb[kbase + (size_t)(k0 + 64 + srow) * 1024];
      p1 = *(const uint4*)&Kb[kbase + (size_t)(k0 + 96 + srow) * 1024];
    }
#pragma unroll
    for (int n = 0; n < 4; ++n) {
      bf16x8 bk0 = *(const bf16x8*)&lK[cur][(n * 16 + l15) * 72 + quad * 8];
      bf16x8 bk1 = *(const bf16x8*)&lK[cur][(n * 16 + l15) * 72 + 32 + quad * 8];
      f32x4 s = MFMA16(bk0, aq0, ZERO4);
      s = MFMA16(bk1, aq1, s);
      const int keyb = k0 + n * 16 + kq;
      if (c == qt) {
#pragma unroll
        for (int i = 0; i < 4; ++i)
          lacc += (keyb + i > qrow) ? 0.f : expf_c(s[i]);
      } else {
#pragma unroll
        for (int i = 0; i < 4; ++i) lacc += expf_c(s[i]);
      }
    }
    if (pf) {
      *(uint4*)&lK[cur ^ 1][srow * 72 + sseg] = p0;
      *(uint4*)&lK[cur ^ 1][(32 + srow) * 72 + sseg] = p1;
    }
    __syncthreads();
  }
  // lanes sharing l15 (same q-row) differ in bits 4,5 -> 2-step reduce
  lacc += __shfl_xor(lacc, 16);
  lacc += __shfl_xor(lacc, 32);
  const float invl = 1.0f / fmaxf(lacc, 1e-30f);

  // ---- pass 2: normalized P -> attnF ; O += P·V ; K,V double-buffered ----
  f32x4 o[4];
#pragma unroll
  for (int n = 0; n < 4; ++n) o[n] = ZERO4;
  const size_t arow = ((size_t)bh * 2048 + qrow) * 2048;
  u16* lPw = lP[w];

  {
    uint4 a0 = *(const uint4*)&Kb[kbase + (size_t)srow * 1024];
    uint4 a1 = *(const uint4*)&Kb[kbase + (size_t)(32 + srow) * 1024];
    uint4 b0 = *(const uint4*)&Vt[vbase + (size_t)srow * 2048];
    uint4 b1 = *(const uint4*)&Vt[vbase + (size_t)(32 + srow) * 2048];
    *(uint4*)&lK[0][srow * 72 + sseg] = a0;
    *(uint4*)&lK[0][(32 + srow) * 72 + sseg] = a1;
    *(uint4*)&lV[0][srow * 72 + sseg] = b0;
    *(uint4*)&lV[0][(32 + srow) * 72 + sseg] = b1;
  }
  __syncthreads();
  for (int c = 0; c <= qt; ++c) {
    const int k0 = c * 64, cur = c & 1;
    const bool pf = (c < qt);
    uint4 p0, p1, v0, v1;
    if (pf) {  // issue next-chunk loads early
      p0 = *(const uint4*)&Kb[kbase + (size_t)(k0 + 64 + srow) * 1024];
      p1 = *(const uint4*)&Kb[kbase + (size_t)(k0 + 96 + srow) * 1024];
      v0 = *(const uint4*)&Vt[vbase + (size_t)srow * 2048 + k0 + 64];
      v1 = *(const uint4*)&Vt[vbase + (size_t)(32 + srow) * 2048 + k0 + 64];
    }
    const bool diag = (c == qt);
#pragma unroll
    for (int n = 0; n < 4; ++n) {
      bf16x8 bk0 = *(const bf16x8*)&lK[cur][(n * 16 + l15) * 72 + quad * 8];
      bf16x8 bk1 = *(const bf16x8*)&lK[cur][(n * 16 + l15) * 72 + 32 + quad * 8];
      f32x4 s = MFMA16(bk0, aq0, ZERO4);
      s = MFMA16(bk1, aq1, s);
      const int keyb = k0 + n * 16 + kq;
#pragma unroll
      for (int i = 0; i < 4; ++i) {
        float pv = expf_c(s[i]) * invl;
        if (diag && keyb + i > qrow) pv = 0.f;  // causal mask (exact zero)
        s[i] = pv;
      }
      *(f32x4*)&attnF[arow + keyb] = s;        // 16B coalesced, final value
      ushort4 pk;
      pk.x = f2bf(s[0]); pk.y = f2bf(s[1]); pk.z = f2bf(s[2]); pk.w = f2bf(s[3]);
      *(ushort4*)&lPw[l15 * 72 + n * 16 + kq] = pk;  // P[q_local][key_local]
    }
    // lP is wave-private: RAW through LDS within a wave needs no barrier.
#pragma unroll
    for (int kkk = 0; kkk < 2; ++kkk) {
      bf16x8 ap = *(const bf16x8*)&lPw[l15 * 72 + kkk * 32 + quad * 8];
#pragma unroll
      for (int n = 0; n < 4; ++n) {
        bf16x8 bv = *(const bf16x8*)&lV[cur][(n * 16 + l15) * 72 + kkk * 32 + quad * 8];
        o[n] = MFMA16(ap, bv, o[n]);
      }
    }
    if (pf) {
      *(uint4*)&lK[cur ^ 1][srow * 72 + sseg] = p0;
      *(uint4*)&lK[cur ^ 1][(32 + srow) * 72 + sseg] = p1;
      *(uint4*)&lV[cur ^ 1][srow * 72 + sseg] = v0;
      *(uint4*)&lV[cur ^ 1][(32 + srow) * 72 + sseg] = v1;
    }
    __syncthreads();
  }

  // ---- write O tile (bf16, row-major [b*T+t][D]) via LDS for coalescing ----
  // o[n][i]: q_local = quad*4+i, e_local = n*16+l15 (already normalized)
#pragma unroll
  for (int n = 0; n < 4; ++n)
#pragma unroll
    for (int i = 0; i < 4; ++i) {
      float ov = o[n][i];
      if (!(ov == ov)) ov = 0.f;  // sanitize: guarantee finite output
      lPw[(quad * 4 + i) * 72 + n * 16 + l15] = f2bf(ov);
    }
  {
    int prow = lane >> 3, pseg = (lane & 7) * 8;
#pragma unroll
    for (int p2 = 0; p2 < 2; ++p2) {
      int rr = p2 * 8 + prow;
      *(uint4*)&Ob[(size_t)(b * 2048 + q0 + w * 16 + rr) * 1024 + h * 64 + pseg] =
          *(const uint4*)&lPw[rr * 72 + pseg];
    }
  }
}

extern "C" void kernel_launch(void* const* d_in, const int* in_sizes, int n_in,
                              void* d_out, int out_size, void* d_ws, size_t ws_size,
                              hipStream_t stream) {
  const float* q  = (const float*)d_in[0];
  const float* k  = (const float*)d_in[1];
  const float* v  = (const float*)d_in[2];
  const float* Wq = (const float*)d_in[3];
  const float* Wk = (const float*)d_in[4];
  const float* Wv = (const float*)d_in[5];
  const float* Wc = (const float*)d_in[6];
  // d_in[7] = causal mask: computed analytically, unused.

  float* outF  = (float*)d_out;                   // [B*T, D] = 4096x1024 f32
  float* attnF = outF + (size_t)4096 * 1024;      // [B, H, T, T] f32

  const size_t BUF  = (size_t)4096 * 1024;        // u16 elems per staging buffer
  const size_t WBUF = (size_t)1024 * 1024;        // u16 elems per weight buffer
  u16* ws = (u16*)d_ws;
  const bool big_ws = ws_size >= 4 * BUF * sizeof(u16);

  u16 *Qb, *Kb, *Vt, *Ob;
  if (big_ws) {
    Qb = ws; Kb = ws + BUF; Vt = ws + 2 * BUF; Ob = ws + 3 * BUF;
  } else {
    // out region is 16.8 MB f32 = room for two bf16 staging buffers.
    Qb = (u16*)outF; Ob = (u16*)outF + BUF; Kb = ws; Vt = ws + BUF;
  }

  // bf16 copies of inputs live in the attnF region, which is pure scratch
  // until attn_kernel (stream-ordered after proj_qkv) overwrites all of it.
  u16* qbf  = (u16*)attnF;
  u16* kbf  = qbf  + BUF;
  u16* vbf  = kbf  + BUF;
  u16* wqbf = vbf  + BUF;
  u16* wkbf = wqbf + WBUF;
  u16* wvbf = wkbf + WBUF;
  // Wc is converted AFTER attn into the then-dead Vt region (both ws layouts).
  u16* wcbf = Vt;

  dim3 blk(256, 1, 1);

  Cvt6Args ca;
  ca.s0 = q;    ca.s1 = k;    ca.s2 = v;
  ca.s3 = Wq;   ca.s4 = Wk;   ca.s5 = Wv;
  ca.d0 = qbf;  ca.d1 = kbf;  ca.d2 = vbf;
  ca.d3 = wqbf; ca.d4 = wkbf; ca.d5 = wvbf;
  cvt6<<<dim3(2048, 6), blk, 0, stream>>>(ca);

  QKVArgs a;
  a.X0 = qbf;  a.X1 = kbf;  a.X2 = vbf;
  a.W0 = wqbf; a.W1 = wkbf; a.W2 = wvbf;
  a.Y0 = Qb; a.Y1 = Kb; a.Y2 = Vt;
  a.s0 = 0.03125f;  // fold 1/TEMPERATURE = 1/32 into Q projection
  a.s1 = 1.0f; a.s2 = 1.0f;
  proj_qkv<<<dim3(8, 64, 3), blk, 0, stream>>>(a);
  attn_kernel<<<dim3(1024), blk, 0, stream>>>(Qb, Kb, Vt, attnF, Ob);

  // Vt is dead after attn: reuse it for the bf16 copy of Wc.
  cvt_one<<<dim3(512), blk, 0, stream>>>(Wc, wcbf);

  const u16* gemm_src = Ob;
  if (!big_ws) {
    // Kb is dead now; move Ob out of the out region so the final f32 GEMM
    // never reads and writes overlapping memory.
    (void)hipMemcpyAsync(ws, Ob, BUF * sizeof(u16), hipMemcpyDeviceToDevice, stream);
    gemm_src = ws;
  }
  proj_out<<<dim3(8, 64), blk, 0, stream>>>(gemm_src, wcbf, outF);
}